// Round 8
// baseline (199.899 us; speedup 1.0000x reference)
//
#include <hip/hip_runtime.h>
#include <hip/hip_bf16.h>

// ---------------------------------------------------------------------------
// Decoder block on MI355X.
// R8 GEMM core: 128x128 / BK=64 / 4 waves / 64KB LDS -> 2 blocks per CU
// (cross-block stall covering, m97/m114 mechanism), 2 phases per K-tile with
// ONE barrier per phase, counted-vmcnt ledger (4 loads/phase, 8 outstanding,
// VMW(4) each phase). Same XOR-swizzled LDS lines as the proven 256² kernel.
// Attention: swapped-QK^T flash + heavy-first dispatch + defer-max.
// ---------------------------------------------------------------------------

typedef __attribute__((ext_vector_type(8))) short short8;
typedef __attribute__((ext_vector_type(4))) short short4v;
typedef __attribute__((ext_vector_type(4))) float f32x4;

#define DEVI static __device__ __forceinline__

#define BAR() __builtin_amdgcn_s_barrier()
#define SB0() __builtin_amdgcn_sched_barrier(0)
#define LGKM0()                                         \
  {                                                     \
    asm volatile("s_waitcnt lgkmcnt(0)" ::: "memory");  \
    __builtin_amdgcn_sched_barrier(0);                  \
  }
#define VMW(n)                                              \
  {                                                         \
    asm volatile("s_waitcnt vmcnt(" #n ")" ::: "memory");   \
    __builtin_amdgcn_sched_barrier(0);                      \
  }

DEVI void gload_lds16(const void* g, void* l) {
  __builtin_amdgcn_global_load_lds(
      (const __attribute__((address_space(1))) void*)g,
      (__attribute__((address_space(3))) void*)l, 16, 0, 0);
}

DEVI float bf2f(short s) {
  union { float f; unsigned u; } cv;
  cv.u = ((unsigned)(unsigned short)s) << 16;
  return cv.f;
}
DEVI short f2bf(float f) {  // round-to-nearest-even
  union { float f; unsigned u; } cv;
  cv.f = f;
  unsigned u = cv.u;
  u += 0x7FFFu + ((u >> 16) & 1u);
  return (short)(u >> 16);
}

DEVI void block_reduce2(float& s, float& s2, float* red, int t) {
#pragma unroll
  for (int off = 1; off < 64; off <<= 1) {
    s += __shfl_xor(s, off, 64);
    s2 += __shfl_xor(s2, off, 64);
  }
  __syncthreads();
  if ((t & 63) == 0) { red[(t >> 6) * 2] = s; red[(t >> 6) * 2 + 1] = s2; }
  __syncthreads();
  s = red[0] + red[2] + red[4] + red[6];
  s2 = red[1] + red[3] + red[5] + red[7];
}

// bijective XCD swizzle: nwg must be divisible by 8 (all our GEMM grids are).
DEVI void xcd_swz(int gx, int gy, int& bx, int& by) {
  const int flat = blockIdx.y * gx + blockIdx.x;
  const int c = (gx * gy) >> 3;
  const int nf = (flat & 7) * c + (flat >> 3);
  bx = nf % gx;
  by = nf / gx;
}

// --------------------------- transpose f32 -> bf16 -------------------------
__global__ __launch_bounds__(256) void transpose_to_bf16(
    const float* __restrict__ in, short* __restrict__ out, int R, int C) {
  __shared__ float tile[32][33];
  const int b = blockIdx.z;
  in += (size_t)b * R * C;
  out += (size_t)b * R * C;
  const int r0 = blockIdx.y * 32, c0 = blockIdx.x * 32;
  const int tx = threadIdx.x, ty = threadIdx.y;
#pragma unroll
  for (int i = 0; i < 32; i += 8)
    tile[ty + i][tx] = in[(size_t)(r0 + ty + i) * C + c0 + tx];
  __syncthreads();
#pragma unroll
  for (int i = 0; i < 32; i += 8)
    out[(size_t)(c0 + ty + i) * R + r0 + tx] = f2bf(tile[tx][ty + i]);
}

// Wq/Wk/Wv merged: each [16][1024][64] -> wqkv_t [3][16][64][1024]
__global__ __launch_bounds__(256) void transpose_qkv(
    const float* __restrict__ Wq, const float* __restrict__ Wk,
    const float* __restrict__ Wv, short* __restrict__ out) {
  __shared__ float tile[32][33];
  const int z = blockIdx.z;  // 0..47
  const int sel = z >> 4, b = z & 15;
  const float* in = (sel == 0) ? Wq : (sel == 1) ? Wk : Wv;
  in += (size_t)b * 1024 * 64;
  short* o = out + (size_t)sel * 1024 * 1024 + (size_t)b * 1024 * 64;
  const int r0 = blockIdx.y * 32, c0 = blockIdx.x * 32;
  const int tx = threadIdx.x, ty = threadIdx.y;
#pragma unroll
  for (int i = 0; i < 32; i += 8)
    tile[ty + i][tx] = in[(size_t)(r0 + ty + i) * 64 + c0 + tx];
  __syncthreads();
#pragma unroll
  for (int i = 0; i < 32; i += 8)
    o[(size_t)(c0 + ty + i) * 1024 + r0 + tx] = f2bf(tile[tx][ty + i]);
}

// ------------------------------- LayerNorms --------------------------------
__global__ __launch_bounds__(256) void ln1_kernel(
    const float* __restrict__ x, const float* __restrict__ g,
    const float* __restrict__ b, float* __restrict__ hf,
    short* __restrict__ hb) {
  __shared__ float red[8];
  const int row = blockIdx.x, t = threadIdx.x;
  float4 v = ((const float4*)(x + (size_t)row * 1024))[t];
  float s = v.x + v.y + v.z + v.w;
  float s2 = v.x * v.x + v.y * v.y + v.z * v.z + v.w * v.w;
  block_reduce2(s, s2, red, t);
  const float mu = s * (1.0f / 1024.0f);
  const float rstd = rsqrtf(s2 * (1.0f / 1024.0f) - mu * mu + 1e-5f);
  float4 gv = ((const float4*)g)[t], bv = ((const float4*)b)[t];
  float4 o;
  o.x = (v.x - mu) * rstd * gv.x + bv.x;
  o.y = (v.y - mu) * rstd * gv.y + bv.y;
  o.z = (v.z - mu) * rstd * gv.z + bv.z;
  o.w = (v.w - mu) * rstd * gv.w + bv.w;
  ((float4*)(hf + (size_t)row * 1024))[t] = o;
  short4v p = {f2bf(o.x), f2bf(o.y), f2bf(o.z), f2bf(o.w)};
  ((short4v*)(hb + (size_t)row * 1024))[t] = p;
}

__global__ __launch_bounds__(256) void ln2f_kernel(
    const float* __restrict__ h, const float* __restrict__ o,
    const float* __restrict__ g2, const float* __restrict__ b2,
    const float* __restrict__ gf, const float* __restrict__ bfp,
    float* __restrict__ x3, short* __restrict__ hfb) {
  __shared__ float red[8];
  const int row = blockIdx.x, t = threadIdx.x;
  float4 hv = ((const float4*)(h + (size_t)row * 1024))[t];
  float4 ov = ((const float4*)(o + (size_t)row * 1024))[t];
  float4 v;
  v.x = hv.x + ov.x; v.y = hv.y + ov.y; v.z = hv.z + ov.z; v.w = hv.w + ov.w;
  float s = v.x + v.y + v.z + v.w;
  float s2 = v.x * v.x + v.y * v.y + v.z * v.z + v.w * v.w;
  block_reduce2(s, s2, red, t);
  float mu = s * (1.0f / 1024.0f);
  float rstd = rsqrtf(s2 * (1.0f / 1024.0f) - mu * mu + 1e-5f);
  float4 gv = ((const float4*)g2)[t], bv = ((const float4*)b2)[t];
  float4 xv;
  xv.x = (v.x - mu) * rstd * gv.x + bv.x;
  xv.y = (v.y - mu) * rstd * gv.y + bv.y;
  xv.z = (v.z - mu) * rstd * gv.z + bv.z;
  xv.w = (v.w - mu) * rstd * gv.w + bv.w;
  ((float4*)(x3 + (size_t)row * 1024))[t] = xv;
  s = xv.x + xv.y + xv.z + xv.w;
  s2 = xv.x * xv.x + xv.y * xv.y + xv.z * xv.z + xv.w * xv.w;
  block_reduce2(s, s2, red, t);
  mu = s * (1.0f / 1024.0f);
  rstd = rsqrtf(s2 * (1.0f / 1024.0f) - mu * mu + 1e-5f);
  float4 gv2 = ((const float4*)gf)[t], bv2 = ((const float4*)bfp)[t];
  short4v pk = {f2bf((xv.x - mu) * rstd * gv2.x + bv2.x),
                f2bf((xv.y - mu) * rstd * gv2.y + bv2.y),
                f2bf((xv.z - mu) * rstd * gv2.z + bv2.z),
                f2bf((xv.w - mu) * rstd * gv2.w + bv2.w)};
  ((short4v*)(hfb + (size_t)row * 1024))[t] = pk;
}

// --------------------- 128x128 2-phase GEMM core (R8) ----------------------
// C[M][N] = A[M][K] * B^T[N][K], bf16, f32 acc. BM=BN=128, BK=64, 4 waves
// (2x2, each 64x64), 256 threads, 64KB LDS -> 2 blocks/CU.
// Per K-tile: 2 phases (one per K-half of 32). Phase p = (t,kh):
//   ds_read 8 frags of half kh | stage A,B half kh of tile t+1 (4 gloads)
//   | lgkmcnt(0) | 16 MFMA | VMW(4) | BAR.
// Ledger: 8 loads outstanding max; VMW(4) retires exactly the half the next
// phase reads. One barrier per phase is sufficient: any wave past BAR(p) has
// executed LGKM0(p-1), so regions overwritten by stage(p+1) are drained.
template <int EPI>
DEVI void gemm4_body(const short* __restrict__ A, const short* __restrict__ B,
                     int K, int kbase, int ktiles, int m0, int n0,
                     const float* __restrict__ f0, const float* __restrict__ f1,
                     const float* __restrict__ f2, short* __restrict__ s0,
                     short* __restrict__ s1, short* __restrict__ s2,
                     float* __restrict__ fo) {
  extern __shared__ __align__(16) char lds[];  // 65536 B
  const int tid = threadIdx.x;
  const int l = tid & 63, w = tid >> 6;  // w in [0,4)
  const int wrM = w >> 1, wcN = w & 1;
  const int lr = l & 15, lg = l >> 4;

  // read-side byte offset within an [64 lines][128B] K-half block
  const int cswz = (((lr & 1) << 2) | lg) ^ (lr >> 1);
  const int laneoff = ((lr >> 1) << 7) + (cswz << 4);

  // stage-side pre-swizzled global source (wave w covers rows [16w,16w+16)
  // per load; second load +64 rows)
  const int rsel = l >> 3;
  const int scz = (l & 7) ^ rsel;
  const int s_roff = w * 16 + rsel * 2 + (scz >> 2);
  const int s_kc = (scz & 3) * 8;
  const short* Asrc = A + (size_t)(m0 + s_roff) * K + kbase + s_kc;
  const short* Bsrc = B + (size_t)(n0 + s_roff) * K + kbase + s_kc;
  const size_t rstep = (size_t)64 * K;

  auto STAGE = [&](int op, int kh, int t) {
    const short* g = (op ? Bsrc : Asrc) + t * 64 + kh * 32;
    char* d = lds + ((t & 1) * 32768 + op * 16384 + kh * 8192 + w * 1024);
    gload_lds16(g, d);
    gload_lds16(g + rstep, d + 4096);
  };

  f32x4 acc[4][4] = {};

  // prologue: tile 0, all 4 halves (8 loads); VMW(4) -> half0 landed.
  STAGE(0, 0, 0); STAGE(1, 0, 0); STAGE(0, 1, 0); STAGE(1, 1, 0);
  VMW(4); BAR(); SB0();

  for (int t = 0; t < ktiles; ++t) {
    const bool st = (t + 1) < ktiles;
#pragma unroll
    for (int kh = 0; kh < 2; ++kh) {
      const char* pa = lds + (t & 1) * 32768 + kh * 8192 + wrM * 4096 + laneoff;
      const char* pb =
          lds + (t & 1) * 32768 + 16384 + kh * 8192 + wcN * 4096 + laneoff;
      short8 a[4], b[4];
#pragma unroll
      for (int mt = 0; mt < 4; ++mt) a[mt] = *(const short8*)(pa + mt * 1024);
#pragma unroll
      for (int nt = 0; nt < 4; ++nt) b[nt] = *(const short8*)(pb + nt * 1024);
      if (st) { STAGE(0, kh, t + 1); STAGE(1, kh, t + 1); }
      LGKM0();
      __builtin_amdgcn_s_setprio(1);
#pragma unroll
      for (int mt = 0; mt < 4; ++mt)
#pragma unroll
        for (int nt = 0; nt < 4; ++nt)
          acc[mt][nt] = __builtin_amdgcn_mfma_f32_16x16x32_bf16(
              a[mt], b[nt], acc[mt][nt], 0, 0, 0);
      __builtin_amdgcn_s_setprio(0);
      if (st) { VMW(4); } else if (kh == 0) { VMW(0); }
      BAR(); SB0();
    }
  }

  // --------------------------- epilogue ---------------------------
#pragma unroll
  for (int mt = 0; mt < 4; ++mt) {
#pragma unroll
    for (int nt = 0; nt < 4; ++nt) {
      const int col = n0 + wcN * 64 + nt * 16 + lr;
      const int row0 = m0 + wrM * 64 + mt * 16 + lg * 4;
      if constexpr (EPI == 0) {  // QKV scatter
        const int sel = col >> 10, nn = col & 1023;
        const int hh = nn >> 6, dd = nn & 63;
        const int bb = row0 >> 10, tt0 = row0 & 1023;
        if (sel == 2) {
          const float bias = f2[nn];
          short4v pk = {f2bf(acc[mt][nt][0] + bias), f2bf(acc[mt][nt][1] + bias),
                        f2bf(acc[mt][nt][2] + bias), f2bf(acc[mt][nt][3] + bias)};
          *(short4v*)&s2[(((size_t)(bb * 16 + hh)) * 64 + dd) * 1024 + tt0] = pk;
        } else {
          const float bias = (sel == 0) ? f0[nn] : f1[nn];
          short* dst = (sel == 0) ? s0 : s1;
#pragma unroll
          for (int r = 0; r < 4; ++r)
            dst[(((size_t)(bb * 16 + hh)) * 1024 + tt0 + r) * 64 + dd] =
                f2bf(acc[mt][nt][r] + bias);
        }
      } else if constexpr (EPI == 1) {  // FFN1 bias+relu -> bf16
#pragma unroll
        for (int r = 0; r < 4; ++r) {
          float val = fmaxf(acc[mt][nt][r] + f0[col], 0.0f);
          s0[(size_t)(row0 + r) * 4096 + col] = f2bf(val);
        }
      } else {  // split-K partials f32
#pragma unroll
        for (int r = 0; r < 4; ++r)
          fo[(size_t)(row0 + r) * 1024 + col] = acc[mt][nt][r];
      }
    }
  }
}

__global__ __launch_bounds__(256, 2) void gemm4_qkv(
    const short* __restrict__ A, const short* __restrict__ B,
    const float* __restrict__ bq, const float* __restrict__ bk,
    const float* __restrict__ bv, short* __restrict__ q,
    short* __restrict__ k, short* __restrict__ vt) {
  int bx, by;
  xcd_swz(24, 32, bx, by);
  gemm4_body<0>(A, B, 1024, 0, 16, by * 128, bx * 128, bq, bk, bv, q, k, vt,
                nullptr);
}

__global__ __launch_bounds__(256, 2) void gemm4_ffn1(
    const short* __restrict__ A, const short* __restrict__ B,
    const float* __restrict__ b1f, short* __restrict__ u) {
  int bx, by;
  xcd_swz(32, 32, bx, by);
  gemm4_body<1>(A, B, 1024, 0, 16, by * 128, bx * 128, b1f, nullptr, nullptr,
                u, nullptr, nullptr, nullptr);
}

// split-K x2: z in [0,2), K-chunk of 2048 over K=4096; writes f32 partials.
__global__ __launch_bounds__(256, 2) void gemm4_ffn2sk(
    const short* __restrict__ A, const short* __restrict__ B,
    float* __restrict__ part) {
  const int z = blockIdx.z;
  int bx, by;
  xcd_swz(8, 32, bx, by);
  gemm4_body<2>(A, B, 4096, z * 2048, 32, by * 128, bx * 128, nullptr, nullptr,
                nullptr, nullptr, nullptr, nullptr,
                part + (size_t)z * 4096 * 1024);
}

// out = part[0] + part[1] + b2f + hf + x3
__global__ __launch_bounds__(256) void ffn2_reduce(
    const float* __restrict__ part, const float* __restrict__ b2f,
    const short* __restrict__ hfb, const float* __restrict__ x3,
    float* __restrict__ out) {
  const size_t i = (size_t)blockIdx.x * 256 + threadIdx.x;
  const size_t S = (size_t)4096 * 1024 / 4;
  float4 a0 = ((const float4*)part)[i];
  float4 a1 = ((const float4*)part)[i + S];
  float4 bb = ((const float4*)b2f)[i & 255];
  float4 xv = ((const float4*)x3)[i];
  short4v hv = ((const short4v*)hfb)[i];
  float4 o;
  o.x = a0.x + a1.x + bb.x + bf2f(hv.x) + xv.x;
  o.y = a0.y + a1.y + bb.y + bf2f(hv.y) + xv.y;
  o.z = a0.z + a1.z + bb.z + bf2f(hv.z) + xv.z;
  o.w = a0.w + a1.w + bb.w + bf2f(hv.w) + xv.w;
  ((float4*)out)[i] = o;
}

// ----------------------------- flash attention -----------------------------
__global__ __launch_bounds__(256, 5) void attn_kernel(
    const short* __restrict__ q, const short* __restrict__ k,
    const short* __restrict__ vt, float* __restrict__ o) {
  __shared__ __align__(16) short Ksm[64 * 64];
  __shared__ __align__(16) short Vsm[64 * 64];
  __shared__ __align__(16) short Psm[4 * 16 * 64];
  const int bh = blockIdx.x;
  const int qt = 15 - blockIdx.y;  // heavy blocks dispatch FIRST
  const int tid = threadIdx.x, lane = tid & 63, w = tid >> 6;
  const int lr = lane & 15, lg = lane >> 4;

  const short* qb = q + (size_t)bh * 1024 * 64;
  const short* kb = k + (size_t)bh * 1024 * 64;
  const short* vb = vt + (size_t)bh * 64 * 1024;

  const int qrow = qt * 64 + w * 16 + lr;
  short8 qf0 = *(const short8*)&qb[(size_t)qrow * 64 + lg * 8];
  short8 qf1 = *(const short8*)&qb[(size_t)qrow * 64 + 32 + lg * 8];

  f32x4 oacc[4] = {};
  float mrun = -1e30f, lrun = 0.0f;

  const float scale2 = 0.03125f * 1.44269504088896f;  // (1/sqrt(C))*log2(e)
  const int srow = tid >> 3;
  const int sc8 = tid & 7;
  char* pw = (char*)(Psm + w * 1024);
  const int qloc = w * 16 + lr;
  const int rowswz = (lr & 7) << 4;

  short8 kreg[2], vreg[2];
#pragma unroll
  for (int p = 0; p < 2; ++p) {
    const int rr = srow + p * 32;
    kreg[p] = *(const short8*)&kb[(size_t)rr * 64 + sc8 * 8];
    vreg[p] = *(const short8*)&vb[(size_t)rr * 1024 + sc8 * 8];
  }

  for (int kt = 0; kt <= qt; ++kt) {
#pragma unroll
    for (int p = 0; p < 2; ++p) {
      const int rr = srow + p * 32;
      *(short8*)((char*)Ksm + rr * 128 + ((sc8 ^ (rr & 7)) << 4)) = kreg[p];
      *(short8*)((char*)Vsm + rr * 128 + ((sc8 ^ (rr & 7)) << 4)) = vreg[p];
    }
    __syncthreads();
    if (kt < qt) {
#pragma unroll
      for (int p = 0; p < 2; ++p) {
        const int rr = srow + p * 32;
        kreg[p] =
            *(const short8*)&kb[((size_t)((kt + 1) * 64 + rr)) * 64 + sc8 * 8];
        vreg[p] =
            *(const short8*)&vb[(size_t)rr * 1024 + (kt + 1) * 64 + sc8 * 8];
      }
    }

    f32x4 sfr[4];
#pragma unroll
    for (int nt = 0; nt < 4; ++nt) {
      const int krow = nt * 16 + lr;
      short8 kf0 = *(const short8*)((const char*)Ksm + krow * 128 +
                                    (((0 + lg) ^ (krow & 7)) << 4));
      short8 kf1 = *(const short8*)((const char*)Ksm + krow * 128 +
                                    (((4 + lg) ^ (krow & 7)) << 4));
      f32x4 z = {};
      z = __builtin_amdgcn_mfma_f32_16x16x32_bf16(kf0, qf0, z, 0, 0, 0);
      z = __builtin_amdgcn_mfma_f32_16x16x32_bf16(kf1, qf1, z, 0, 0, 0);
      sfr[nt] = z;
    }
    if (kt == qt) {
#pragma unroll
      for (int nt = 0; nt < 4; ++nt) {
        const int kb0 = nt * 16 + lg * 4;
#pragma unroll
        for (int r = 0; r < 4; ++r)
          sfr[nt][r] = (kb0 + r <= qloc) ? sfr[nt][r] * scale2 : -1e30f;
      }
    } else {
#pragma unroll
      for (int nt = 0; nt < 4; ++nt)
#pragma unroll
        for (int r = 0; r < 4; ++r) sfr[nt][r] *= scale2;
    }
    float pm;
    {
      float a0 = fmaxf(fmaxf(sfr[0][0], sfr[0][1]), fmaxf(sfr[0][2], sfr[0][3]));
      float a1 = fmaxf(fmaxf(sfr[1][0], sfr[1][1]), fmaxf(sfr[1][2], sfr[1][3]));
      float a2 = fmaxf(fmaxf(sfr[2][0], sfr[2][1]), fmaxf(sfr[2][2], sfr[2][3]));
      float a3 = fmaxf(fmaxf(sfr[3][0], sfr[3][1]), fmaxf(sfr[3][2], sfr[3][3]));
      pm = fmaxf(fmaxf(a0, a1), fmaxf(a2, a3));
      pm = fmaxf(pm, __shfl_xor(pm, 16, 64));
      pm = fmaxf(pm, __shfl_xor(pm, 32, 64));
    }
    if (!__all(pm - mrun <= 8.0f)) {
      const float mnew = fmaxf(mrun, pm);
      const float alpha = exp2f(mrun - mnew);
      mrun = mnew;
      lrun *= alpha;
#pragma unroll
      for (int nt = 0; nt < 4; ++nt)
#pragma unroll
        for (int r = 0; r < 4; ++r) oacc[nt][r] *= alpha;
    }
    float rs;
    {
#pragma unroll
      for (int nt = 0; nt < 4; ++nt)
#pragma unroll
        for (int r = 0; r < 4; ++r) sfr[nt][r] = exp2f(sfr[nt][r] - mrun);
      float s0 = (sfr[0][0] + sfr[0][1]) + (sfr[0][2] + sfr[0][3]);
      float s1 = (sfr[1][0] + sfr[1][1]) + (sfr[1][2] + sfr[1][3]);
      float s2 = (sfr[2][0] + sfr[2][1]) + (sfr[2][2] + sfr[2][3]);
      float s3 = (sfr[3][0] + sfr[3][1]) + (sfr[3][2] + sfr[3][3]);
      rs = (s0 + s1) + (s2 + s3);
      rs += __shfl_xor(rs, 16, 64);
      rs += __shfl_xor(rs, 32, 64);
    }
    lrun += rs;

#pragma unroll
    for (int nt = 0; nt < 4; ++nt) {
      unsigned w0, w1;
      asm("v_cvt_pk_bf16_f32 %0, %1, %2"
          : "=v"(w0) : "v"(sfr[nt][0]), "v"(sfr[nt][1]));
      asm("v_cvt_pk_bf16_f32 %0, %1, %2"
          : "=v"(w1) : "v"(sfr[nt][2]), "v"(sfr[nt][3]));
      uint2 pk2 = {w0, w1};
      *(uint2*)(pw + lr * 128 + ((nt * 32 + lg * 8) ^ rowswz)) = pk2;
    }

#pragma unroll
    for (int kc = 0; kc < 2; ++kc) {
      short8 pb8 = *(const short8*)(pw + lr * 128 + ((kc * 64 + lg * 16) ^ rowswz));
#pragma unroll
      for (int nt = 0; nt < 4; ++nt) {
        const int vrow = nt * 16 + lr;
        short8 vf = *(const short8*)((const char*)Vsm + vrow * 128 +
                                     (((kc * 4 + lg) ^ (vrow & 7)) << 4));
        oacc[nt] = __builtin_amdgcn_mfma_f32_16x16x32_bf16(vf, pb8, oacc[nt], 0, 0, 0);
      }
    }
    __syncthreads();
  }

  const float inv = 1.0f / lrun;
  float* ob = o + (size_t)(bh >> 4) * 1024 * 1024 +
              (size_t)(qt * 64 + qloc) * 1024 + (bh & 15) * 64;
#pragma unroll
  for (int nt = 0; nt < 4; ++nt) {
    float4 ov = {oacc[nt][0] * inv, oacc[nt][1] * inv, oacc[nt][2] * inv,
                 oacc[nt][3] * inv};
    *(float4*)&ob[nt * 16 + lg * 4] = ov;
  }
}

// ------------------------------- launcher ----------------------------------
extern "C" void kernel_launch(void* const* d_in, const int* in_sizes, int n_in,
                              void* d_out, int out_size, void* d_ws,
                              size_t ws_size, hipStream_t stream) {
  const float* x = (const float*)d_in[0];
  const float* Wq = (const float*)d_in[1];
  const float* bq = (const float*)d_in[2];
  const float* Wk = (const float*)d_in[3];
  const float* bk = (const float*)d_in[4];
  const float* Wv = (const float*)d_in[5];
  const float* bv = (const float*)d_in[6];
  const float* g1 = (const float*)d_in[7];
  const float* b1 = (const float*)d_in[8];
  const float* g2 = (const float*)d_in[9];
  const float* b2 = (const float*)d_in[10];
  const float* gf = (const float*)d_in[11];
  const float* bfp = (const float*)d_in[12];
  const float* W1 = (const float*)d_in[13];
  const float* b1f = (const float*)d_in[14];
  const float* W2 = (const float*)d_in[15];
  const float* b2f = (const float*)d_in[16];
  float* out = (float*)d_out;

  hipFuncSetAttribute((const void*)gemm4_qkv,
                      hipFuncAttributeMaxDynamicSharedMemorySize, 65536);
  hipFuncSetAttribute((const void*)gemm4_ffn1,
                      hipFuncAttributeMaxDynamicSharedMemorySize, 65536);
  hipFuncSetAttribute((const void*)gemm4_ffn2sk,
                      hipFuncAttributeMaxDynamicSharedMemorySize, 65536);

  const size_t MB = 1024 * 1024;
  char* p = (char*)d_ws;
  // Region A (70MB): dead before gemm4_ffn2sk; 32MB split-K partials alias it.
  float* hbuf = (float*)(p + 0 * MB);      // 16MB  h (f32), dead after ln2f
  short* qbuf = (short*)(p + 16 * MB);     // 8MB   dead after attn
  short* kbuf = (short*)(p + 24 * MB);     // 8MB   dead after attn
  short* vtb = (short*)(p + 32 * MB);      // 8MB   dead after attn
  float* obuf = (float*)(p + 40 * MB);     // 16MB  dead after ln2f
  short* wqkv_t = (short*)(p + 56 * MB);   // 6MB   dead after gemm4_qkv
  short* w1_t = (short*)(p + 62 * MB);     // 8MB   dead after gemm4_ffn1
  float* part = (float*)(p + 0 * MB);      // 32MB  alias
  // Region B (72MB): live through the end.
  char* q = p + 70 * MB;
  short* w2_t = (short*)(q + 0 * MB);      // 8MB
  short* hbb = (short*)(q + 8 * MB);       // 8MB
  float* x3b = (float*)(q + 16 * MB);      // 16MB
  short* hfb = (short*)(q + 32 * MB);      // 8MB
  short* ub = (short*)(q + 40 * MB);       // 32MB

  dim3 tb(32, 8);
  transpose_qkv<<<dim3(2, 32, 48), tb, 0, stream>>>(Wq, Wk, Wv, wqkv_t);
  transpose_to_bf16<<<dim3(128, 32, 1), tb, 0, stream>>>(W1, w1_t, 1024, 4096);
  transpose_to_bf16<<<dim3(32, 128, 1), tb, 0, stream>>>(W2, w2_t, 4096, 1024);

  ln1_kernel<<<4096, 256, 0, stream>>>(x, g1, b1, hbuf, hbb);

  gemm4_qkv<<<dim3(24, 32), 256, 65536, stream>>>(hbb, wqkv_t, bq, bk, bv,
                                                  qbuf, kbuf, vtb);

  attn_kernel<<<dim3(64, 16), 256, 0, stream>>>(qbuf, kbuf, vtb, obuf);

  ln2f_kernel<<<4096, 256, 0, stream>>>(hbuf, obuf, g2, b2, gf, bfp, x3b, hfb);

  gemm4_ffn1<<<dim3(32, 32), 256, 65536, stream>>>(hfb, w1_t, b1f, ub);

  gemm4_ffn2sk<<<dim3(8, 32, 2), 256, 65536, stream>>>(ub, w2_t, part);

  ffn2_reduce<<<4096, 256, 0, stream>>>(part, b2f, hfb, x3b, out);
}